// Round 12
// baseline (408.244 us; speedup 1.0000x reference)
//
#include <hip/hip_runtime.h>
#include <math.h>

#define D 128
#define LN_EPS 1e-5f

#define NB_SHIFT 7                   // 128 nodes per bucket
#define BIN_EPT 16                   // edges per thread in hist/bin passes
#define BIN_CHUNK (BIN_EPT * 256)    // 4096 edges per block
#define MAXB 800                     // >= NB (782)
#define SRC_BITS 25                  // pack: (dloc << 25) | src  (src < 2^25)
#define TS 136                       // out-tile stride (ushorts): rows 16B-aligned

typedef unsigned short ushort_t;
typedef unsigned int uint_t;
typedef __attribute__((ext_vector_type(8))) short bf16x8;
typedef __attribute__((ext_vector_type(8))) unsigned short u16x8;
typedef __attribute__((ext_vector_type(4))) float f32x4;

static __device__ __forceinline__ float bf2f(ushort_t u) {
    union { uint_t i; float f; } c; c.i = ((uint_t)u) << 16; return c.f;
}
static __device__ __forceinline__ ushort_t f2bf(float f) {
    union { float f; uint_t i; } c; c.f = f;
    uint_t u = c.i;
    uint_t r = (u + 0x7fffu + ((u >> 16) & 1u)) >> 16;   // RNE
    return (ushort_t)r;
}

// ---------------- fused prep: 4 bf16 casts + bucket histogram in one launch ---
// Block-range partition: [0,bx) cast x | [bx,bwl) wl | [bwl,bwr) wr |
// [bwr,bw1) w1 | [bw1,...) bucket hist. All element counts are multiples of
// 2048 so cast branches have no tail handling.
__global__ __launch_bounds__(256) void prep_kernel(
    const float* __restrict__ x, ushort_t* __restrict__ x_bf,
    const float* __restrict__ wl, ushort_t* __restrict__ wl_bf,
    const float* __restrict__ wr, ushort_t* __restrict__ wr_bf,
    const float* __restrict__ w1, ushort_t* __restrict__ w1_bf,
    const int* __restrict__ ei, int E, int* __restrict__ bcnt, int nb,
    int bx, int bwl, int bwr, int bw1) {
    __shared__ int h[MAXB];
    const int b = blockIdx.x;
    const int tid = threadIdx.x;

    if (b < bw1) {
        const float* __restrict__ in;
        ushort_t* __restrict__ outp;
        int rel;
        if (b < bx)       { in = x;  outp = x_bf;  rel = b; }
        else if (b < bwl) { in = wl; outp = wl_bf; rel = b - bx; }
        else if (b < bwr) { in = wr; outp = wr_bf; rel = b - bwl; }
        else              { in = w1; outp = w1_bf; rel = b - bwr; }
        int i = (rel * 256 + tid) * 8;
        f32x4 a = __builtin_nontemporal_load((const f32x4*)&in[i]);
        f32x4 c = __builtin_nontemporal_load((const f32x4*)&in[i + 4]);
        u16x8 v;
        v[0] = f2bf(a.x); v[1] = f2bf(a.y); v[2] = f2bf(a.z); v[3] = f2bf(a.w);
        v[4] = f2bf(c.x); v[5] = f2bf(c.y); v[6] = f2bf(c.z); v[7] = f2bf(c.w);
        *(u16x8*)&outp[i] = v;
        return;
    }

    // bucket histogram branch
    for (int i = tid; i < nb; i += 256) h[i] = 0;
    __syncthreads();
    int e0 = (b - bw1) * BIN_CHUNK;
    #pragma unroll
    for (int i = 0; i < BIN_EPT; ++i) {
        int e = e0 + i * 256 + tid;
        if (e < E) {
            int d = __builtin_nontemporal_load(&ei[E + e]);
            atomicAdd(&h[d >> NB_SHIFT], 1);
        }
    }
    __syncthreads();
    for (int i = tid; i < nb; i += 256) {
        int c = h[i];
        if (c) atomicAdd(&bcnt[i], c);
    }
}

__global__ __launch_bounds__(1024) void scan_buckets_kernel(const int* __restrict__ bcnt,
                                                            int* __restrict__ bptr,
                                                            int* __restrict__ bcur, int nb) {
    __shared__ int wt[16];
    const int lane = threadIdx.x & 63;
    const int wid = threadIdx.x >> 6;
    int running = 0;
    for (int base = 0; base < nb; base += 1024) {
        int i = base + (int)threadIdx.x;
        int v = (i < nb) ? bcnt[i] : 0;
        int incl = v;
        #pragma unroll
        for (int off = 1; off < 64; off <<= 1) {
            int t = __shfl_up(incl, off, 64);
            if (lane >= off) incl += t;
        }
        if (lane == 63) wt[wid] = incl;
        __syncthreads();
        int prefix = running;
        for (int w = 0; w < wid; ++w) prefix += wt[w];
        if (i < nb) {
            int ex = prefix + incl - v;
            bptr[i] = ex;
            bcur[i] = ex;
        }
        int total = 0;
        for (int w = 0; w < 16; ++w) total += wt[w];
        __syncthreads();
        running += total;
    }
    if (threadIdx.x == 0) bptr[nb] = running;
}

__global__ __launch_bounds__(256) void bin_edges_kernel(const int* __restrict__ ei, int E,
                                                        int* __restrict__ bcur,
                                                        uint_t* __restrict__ pairs, int nb) {
    __shared__ int hist[MAXB];
    __shared__ int base[MAXB];
    const int tid = threadIdx.x;
    for (int i = tid; i < nb; i += 256) hist[i] = 0;
    __syncthreads();

    int e0 = blockIdx.x * BIN_CHUNK;
    int s_r[BIN_EPT], d_r[BIN_EPT], idx_r[BIN_EPT];
    #pragma unroll
    for (int i = 0; i < BIN_EPT; ++i) {
        int e = e0 + i * 256 + tid;
        if (e < E) {
            s_r[i] = __builtin_nontemporal_load(&ei[e]);
            d_r[i] = __builtin_nontemporal_load(&ei[E + e]);
            idx_r[i] = atomicAdd(&hist[d_r[i] >> NB_SHIFT], 1);
        }
    }
    __syncthreads();
    for (int i = tid; i < nb; i += 256) {
        int c = hist[i];
        base[i] = c ? atomicAdd(&bcur[i], c) : 0;
    }
    __syncthreads();
    #pragma unroll
    for (int i = 0; i < BIN_EPT; ++i) {
        int e = e0 + i * 256 + tid;
        if (e < E) {
            int pos = base[d_r[i] >> NB_SHIFT] + idx_r[i];
            uint_t pv = ((uint_t)(d_r[i] & 127) << SRC_BITS) | (uint_t)s_r[i];
            __builtin_nontemporal_store(pv, &pairs[pos]);
        }
    }
}

__global__ __launch_bounds__(256) void bucket_csr_kernel(const uint_t* __restrict__ pairs,
                                                         const int* __restrict__ bptr,
                                                         int* __restrict__ row_ptr,
                                                         int* __restrict__ csr_src,
                                                         int nb, int n) {
    __shared__ int hist[128];
    __shared__ int cur[128];
    __shared__ int wtot[4];
    const int tid = threadIdx.x;
    const int b = blockIdx.x;
    const int e0 = bptr[b];
    const int e1 = bptr[b + 1];
    const int n0 = b << NB_SHIFT;

    if (tid < 128) hist[tid] = 0;
    __syncthreads();
    for (int e = e0 + tid; e < e1; e += 256)
        atomicAdd(&hist[__builtin_nontemporal_load(&pairs[e]) >> SRC_BITS], 1);
    __syncthreads();

    int v = (tid < 128) ? hist[tid] : 0;
    int lane = tid & 63, wv = tid >> 6;
    int incl = v;
    #pragma unroll
    for (int off = 1; off < 64; off <<= 1) {
        int t = __shfl_up(incl, off, 64);
        if (lane >= off) incl += t;
    }
    if (lane == 63) wtot[wv] = incl;
    __syncthreads();
    if (tid < 128) {
        int excl = incl - v + ((wv == 1) ? wtot[0] : 0);
        cur[tid] = excl;
        int node = n0 + tid;
        if (node < n) row_ptr[node] = e0 + excl;
    }
    if (b == nb - 1 && tid == 0) row_ptr[n] = e1;
    __syncthreads();

    for (int e = e0 + tid; e < e1; e += 256) {
        uint_t p = __builtin_nontemporal_load(&pairs[e]);
        int pos = e0 + atomicAdd(&cur[p >> SRC_BITS], 1);
        csr_src[pos] = (int)(p & ((1u << SRC_BITS) - 1u));
    }
}

// ---------------- fused SAGE layer: gather-agg -> LDS -> MFMA -> LN+SiLU ------
// LDS = exactly 32 KB; LN partials + out-tile overlay the stage after the main
// K-loop. Gather: 2-node interleaved pairs per 16-lane group (2 independent
// idx->gather chains, 8 outstanding loads). Gather loads stay CACHED (they are
// the L2-reuse consumer).
__global__ __launch_bounds__(256) void sage_fused(
    const ushort_t* __restrict__ hprev,
    const int* __restrict__ row_ptr, const int* __restrict__ csr_src,
    const ushort_t* __restrict__ Wl, const ushort_t* __restrict__ Wr,
    const float* __restrict__ bl, const float* __restrict__ br,
    const float* __restrict__ lng, const float* __restrict__ lnb,
    ushort_t* __restrict__ hout, int n) {
    __shared__ ushort_t stage[16384];          // 32768 B total
    ushort_t* tile = stage;                                        // 64 x TS, 17408 B
    float (*part_s)[4]  = (float(*)[4])((char*)stage + 17408);     // 1 KB
    float (*part_s2)[4] = (float(*)[4])((char*)stage + 18432);     // 1 KB

    const int tid = threadIdx.x;
    const int w = tid >> 6;
    const int lane = tid & 63;
    const int quad = lane >> 4;
    const int l16 = lane & 15;
    const int n0 = blockIdx.x * 64;

    // phase A: stage own hin rows into upper half (chunk-XOR swizzle)
    #pragma unroll
    for (int i = 0; i < 4; ++i) {
        int g = i * 256 + tid;
        int row = g >> 4, ch = g & 15;
        int gr = n0 + row; if (gr >= n) gr = n - 1;
        u16x8 v = *(const u16x8*)&hprev[(size_t)gr * D + ch * 8];
        *(u16x8*)&stage[8192 + row * 128 + (ch ^ (row & 7)) * 8] = v;
    }

    // phase B: aggregation, 2-node interleaved pairs per 16-lane group
    const int G = tid >> 4;
    #pragma unroll
    for (int kp = 0; kp < 2; ++kp) {
        int rowA = G * 4 + kp * 2;
        int rowB = rowA + 1;
        int nodeA = n0 + rowA;
        int nodeB = n0 + rowB;
        float accA[8] = {0.f, 0.f, 0.f, 0.f, 0.f, 0.f, 0.f, 0.f};
        float accB[8] = {0.f, 0.f, 0.f, 0.f, 0.f, 0.f, 0.f, 0.f};
        int eA = 0, s1A = 0, eB = 0, s1B = 0, dgA = 0, dgB = 0;
        if (nodeA < n) { eA = row_ptr[nodeA]; s1A = row_ptr[nodeA + 1]; dgA = s1A - eA; }
        if (nodeB < n) { eB = row_ptr[nodeB]; s1B = row_ptr[nodeB + 1]; dgB = s1B - eB; }
        while (eA + 4 <= s1A && eB + 4 <= s1B) {
            int ia[4], ib[4];
            #pragma unroll
            for (int j = 0; j < 4; ++j) { ia[j] = csr_src[eA + j]; ib[j] = csr_src[eB + j]; }
            u16x8 va[4], vb[4];
            #pragma unroll
            for (int j = 0; j < 4; ++j)
                va[j] = *(const u16x8*)&hprev[(size_t)ia[j] * D + l16 * 8];
            #pragma unroll
            for (int j = 0; j < 4; ++j)
                vb[j] = *(const u16x8*)&hprev[(size_t)ib[j] * D + l16 * 8];
            #pragma unroll
            for (int i = 0; i < 8; ++i) {
                accA[i] += bf2f(va[0][i]) + bf2f(va[1][i]) + bf2f(va[2][i]) + bf2f(va[3][i]);
                accB[i] += bf2f(vb[0][i]) + bf2f(vb[1][i]) + bf2f(vb[2][i]) + bf2f(vb[3][i]);
            }
            eA += 4; eB += 4;
        }
        for (; eA + 4 <= s1A; eA += 4) {
            int ia[4];
            #pragma unroll
            for (int j = 0; j < 4; ++j) ia[j] = csr_src[eA + j];
            u16x8 va[4];
            #pragma unroll
            for (int j = 0; j < 4; ++j)
                va[j] = *(const u16x8*)&hprev[(size_t)ia[j] * D + l16 * 8];
            #pragma unroll
            for (int i = 0; i < 8; ++i)
                accA[i] += bf2f(va[0][i]) + bf2f(va[1][i]) + bf2f(va[2][i]) + bf2f(va[3][i]);
        }
        for (; eA < s1A; ++eA) {
            u16x8 vv = *(const u16x8*)&hprev[(size_t)csr_src[eA] * D + l16 * 8];
            #pragma unroll
            for (int i = 0; i < 8; ++i) accA[i] += bf2f(vv[i]);
        }
        for (; eB + 4 <= s1B; eB += 4) {
            int ib[4];
            #pragma unroll
            for (int j = 0; j < 4; ++j) ib[j] = csr_src[eB + j];
            u16x8 vb[4];
            #pragma unroll
            for (int j = 0; j < 4; ++j)
                vb[j] = *(const u16x8*)&hprev[(size_t)ib[j] * D + l16 * 8];
            #pragma unroll
            for (int i = 0; i < 8; ++i)
                accB[i] += bf2f(vb[0][i]) + bf2f(vb[1][i]) + bf2f(vb[2][i]) + bf2f(vb[3][i]);
        }
        for (; eB < s1B; ++eB) {
            u16x8 vv = *(const u16x8*)&hprev[(size_t)csr_src[eB] * D + l16 * 8];
            #pragma unroll
            for (int i = 0; i < 8; ++i) accB[i] += bf2f(vv[i]);
        }
        float scA = (dgA > 0) ? (1.0f / (float)dgA) : 0.0f;
        float scB = (dgB > 0) ? (1.0f / (float)dgB) : 0.0f;
        u16x8 oA, oB;
        #pragma unroll
        for (int i = 0; i < 8; ++i) { oA[i] = f2bf(accA[i] * scA); oB[i] = f2bf(accB[i] * scB); }
        *(u16x8*)&stage[rowA * 128 + (l16 ^ (rowA & 7)) * 8] = oA;
        *(u16x8*)&stage[rowB * 128 + (l16 ^ (rowB & 7)) * 8] = oB;
    }
    __syncthreads();

    // phase C: main K=256 MFMA (A from LDS, B from global/L2)
    f32x4 acc[4][2];
    #pragma unroll
    for (int rt = 0; rt < 4; ++rt)
        #pragma unroll
        for (int jl = 0; jl < 2; ++jl) acc[rt][jl] = (f32x4){0.f, 0.f, 0.f, 0.f};

    #pragma unroll
    for (int c = 0; c < 8; ++c) {
        const ushort_t* __restrict__ W = (c < 4) ? Wl : Wr;
        const int kb = (c & 3) * 32;
        const ushort_t* sbase = &stage[(c < 4) ? 0 : 8192];
        const int cl = (c & 3) * 4 + quad;
        bf16x8 bfr[2];
        #pragma unroll
        for (int jl = 0; jl < 2; ++jl) {
            int j = (2 * w + jl) * 16 + l16;
            bfr[jl] = *(const bf16x8*)&W[(size_t)j * D + kb + quad * 8];
        }
        bf16x8 af[4];
        #pragma unroll
        for (int rt = 0; rt < 4; ++rt) {
            int row = rt * 16 + l16;
            af[rt] = *(const bf16x8*)&sbase[row * 128 + ((cl ^ (l16 & 7)) * 8)];
        }
        #pragma unroll
        for (int rt = 0; rt < 4; ++rt)
            #pragma unroll
            for (int jl = 0; jl < 2; ++jl)
                acc[rt][jl] = __builtin_amdgcn_mfma_f32_16x16x32_bf16(af[rt], bfr[jl],
                                                                      acc[rt][jl], 0, 0, 0);
    }
    __syncthreads();   // stage reads done; overlays become writable

    // phase D: bias + cross-wave LN partials
    float bsum[2], g[2], bb[2];
    #pragma unroll
    for (int jl = 0; jl < 2; ++jl) {
        int j = (2 * w + jl) * 16 + l16;
        bsum[jl] = bl[j] + br[j];
        g[jl] = lng[j];
        bb[jl] = lnb[j];
    }
    #pragma unroll
    for (int rt = 0; rt < 4; ++rt) {
        #pragma unroll
        for (int r = 0; r < 4; ++r) {
            float v0 = acc[rt][0][r] + bsum[0];
            float v1 = acc[rt][1][r] + bsum[1];
            acc[rt][0][r] = v0;
            acc[rt][1][r] = v1;
            float s = v0 + v1;
            float s2 = v0 * v0 + v1 * v1;
            #pragma unroll
            for (int off = 1; off < 16; off <<= 1) {
                s += __shfl_xor(s, off, 64);
                s2 += __shfl_xor(s2, off, 64);
            }
            if (l16 == 0) {
                int row = rt * 16 + quad * 4 + r;
                part_s[row][w] = s;
                part_s2[row][w] = s2;
            }
        }
    }
    __syncthreads();

    // finish LN + SiLU, write bf16 out-tile
    #pragma unroll
    for (int rt = 0; rt < 4; ++rt) {
        #pragma unroll
        for (int r = 0; r < 4; ++r) {
            int row = rt * 16 + quad * 4 + r;
            float s = part_s[row][0] + part_s[row][1] + part_s[row][2] + part_s[row][3];
            float s2 = part_s2[row][0] + part_s2[row][1] + part_s2[row][2] + part_s2[row][3];
            float mean = s * (1.0f / 128.0f);
            float var = s2 * (1.0f / 128.0f) - mean * mean;
            float rstd = rsqrtf(var + LN_EPS);
            #pragma unroll
            for (int jl = 0; jl < 2; ++jl) {
                float z = (acc[rt][jl][r] - mean) * rstd * g[jl] + bb[jl];
                float sv = z / (1.0f + expf(-z));
                tile[row * TS + (2 * w + jl) * 16 + l16] = f2bf(sv);
            }
        }
    }
    __syncthreads();
    int row = tid >> 2, seg = tid & 3;
    int node = n0 + row;
    if (node < n) {
        #pragma unroll
        for (int k2 = 0; k2 < 4; ++k2) {
            u16x8 vv = *(const u16x8*)&tile[row * TS + seg * 32 + k2 * 8];
            *(u16x8*)&hout[(size_t)node * D + seg * 32 + k2 * 8] = vv;
        }
    }
}

// ---------------- fused MLP head: LDS-staged A + MFMA + ReLU + dot(w2) -------
__global__ __launch_bounds__(256) void mlp_head_mfma(
    const ushort_t* __restrict__ hin, const ushort_t* __restrict__ W1,
    const float* __restrict__ b1, const float* __restrict__ w2,
    const float* __restrict__ b2, float* __restrict__ out, int n) {
    __shared__ ushort_t stage[64 * 128];
    __shared__ float part[64][4];

    const int tid = threadIdx.x;
    const int w = tid >> 6;
    const int lane = tid & 63;
    const int quad = lane >> 4;
    const int l16 = lane & 15;
    const int n0 = blockIdx.x * 64;

    #pragma unroll
    for (int i = 0; i < 4; ++i) {
        int g = i * 256 + tid;
        int row = g >> 4, ch = g & 15;
        int gr = n0 + row; if (gr >= n) gr = n - 1;
        u16x8 v = *(const u16x8*)&hin[(size_t)gr * D + ch * 8];
        *(u16x8*)&stage[row * 128 + (ch ^ (row & 7)) * 8] = v;
    }
    __syncthreads();

    f32x4 acc[4][2];
    #pragma unroll
    for (int rt = 0; rt < 4; ++rt)
        #pragma unroll
        for (int jl = 0; jl < 2; ++jl) acc[rt][jl] = (f32x4){0.f, 0.f, 0.f, 0.f};

    #pragma unroll
    for (int c = 0; c < 4; ++c) {
        const int kb = c * 32;
        const int cl = c * 4 + quad;
        bf16x8 bfr[2];
        #pragma unroll
        for (int jl = 0; jl < 2; ++jl) {
            int j = (2 * w + jl) * 16 + l16;
            bfr[jl] = *(const bf16x8*)&W1[(size_t)j * D + kb + quad * 8];
        }
        bf16x8 af[4];
        #pragma unroll
        for (int rt = 0; rt < 4; ++rt) {
            int row = rt * 16 + l16;
            af[rt] = *(const bf16x8*)&stage[row * 128 + ((cl ^ (l16 & 7)) * 8)];
        }
        #pragma unroll
        for (int rt = 0; rt < 4; ++rt)
            #pragma unroll
            for (int jl = 0; jl < 2; ++jl)
                acc[rt][jl] = __builtin_amdgcn_mfma_f32_16x16x32_bf16(af[rt], bfr[jl],
                                                                      acc[rt][jl], 0, 0, 0);
    }

    float bias1[2], wv2[2];
    #pragma unroll
    for (int jl = 0; jl < 2; ++jl) {
        int j = (2 * w + jl) * 16 + l16;
        bias1[jl] = b1[j];
        wv2[jl] = w2[j];
    }
    #pragma unroll
    for (int rt = 0; rt < 4; ++rt) {
        #pragma unroll
        for (int r = 0; r < 4; ++r) {
            float p = fmaxf(acc[rt][0][r] + bias1[0], 0.0f) * wv2[0]
                    + fmaxf(acc[rt][1][r] + bias1[1], 0.0f) * wv2[1];
            #pragma unroll
            for (int off = 1; off < 16; off <<= 1) p += __shfl_xor(p, off, 64);
            if (l16 == 0) part[rt * 16 + quad * 4 + r][w] = p;
        }
    }
    __syncthreads();
    if (tid < 64) {
        int node = n0 + tid;
        if (node < n)
            out[node] = part[tid][0] + part[tid][1] + part[tid][2] + part[tid][3] + b2[0];
    }
}

// ---------------- launch ----------------
static inline size_t align_up(size_t v, size_t a) { return (v + a - 1) & ~(a - 1); }

extern "C" void kernel_launch(void* const* d_in, const int* in_sizes, int n_in,
                              void* d_out, int out_size, void* d_ws, size_t ws_size,
                              hipStream_t stream) {
    const float* x       = (const float*)d_in[0];
    const int*   ei      = (const int*)d_in[1];
    const float* lin_l_w = (const float*)d_in[2];
    const float* lin_l_b = (const float*)d_in[3];
    const float* lin_r_w = (const float*)d_in[4];
    const float* lin_r_b = (const float*)d_in[5];
    const float* ln_g    = (const float*)d_in[6];
    const float* ln_b    = (const float*)d_in[7];
    const float* mlp_w1  = (const float*)d_in[8];
    const float* mlp_b1  = (const float*)d_in[9];
    const float* mlp_w2  = (const float*)d_in[10];
    const float* mlp_b2  = (const float*)d_in[11];
    float* out = (float*)d_out;

    const int N = in_sizes[0] / D;   // 100000
    const int E = in_sizes[1] / 2;   // 1600000
    const int NB = (N + (1 << NB_SHIFT) - 1) >> NB_SHIFT;   // 782

    // workspace layout
    char* w = (char*)d_ws;
    size_t off = 0;
    int* bcnt = (int*)(w + off);       off = align_up(off + sizeof(int) * (size_t)(NB + 1), 512);
    int* bptr = (int*)(w + off);       off = align_up(off + sizeof(int) * (size_t)(NB + 1), 512);
    int* bcur = (int*)(w + off);       off = align_up(off + sizeof(int) * (size_t)(NB + 1), 512);
    int* row_ptr = (int*)(w + off);    off = align_up(off + sizeof(int) * (size_t)(N + 1), 512);
    int* csr_src = (int*)(w + off);    off = align_up(off + sizeof(int) * (size_t)E, 512);
    uint_t* pairs = (uint_t*)(w + off); off = align_up(off + sizeof(uint_t) * (size_t)E, 512);
    ushort_t* x_bf = (ushort_t*)(w + off);   off = align_up(off + 2ull * N * D, 512);
    ushort_t* h1_bf = (ushort_t*)(w + off);  off = align_up(off + 2ull * N * D, 512);
    ushort_t* h2_bf = (ushort_t*)(w + off);  off = align_up(off + 2ull * N * D, 512);
    ushort_t* wl_bf = (ushort_t*)(w + off);  off = align_up(off + 2ull * 2 * D * D, 512);
    ushort_t* wr_bf = (ushort_t*)(w + off);  off = align_up(off + 2ull * 2 * D * D, 512);
    ushort_t* w1_bf = (ushort_t*)(w + off);  off = align_up(off + 2ull * D * D, 512);

    hipMemsetAsync(bcnt, 0, sizeof(int) * (size_t)(NB + 1), stream);

    // fused prep: x/wl/wr/w1 casts + bucket histogram (one launch)
    const int bx  = (N * D) / 2048;              // 6250
    const int bwl = bx + (2 * D * D) / 2048;     // +16
    const int bwr = bwl + (2 * D * D) / 2048;    // +16
    const int bw1 = bwr + (D * D) / 2048;        // +8
    const int bin_grid = (E + BIN_CHUNK - 1) / BIN_CHUNK;   // 391
    prep_kernel<<<bw1 + bin_grid, 256, 0, stream>>>(
        x, x_bf, lin_l_w, wl_bf, lin_r_w, wr_bf, mlp_w1, w1_bf,
        ei, E, bcnt, NB, bx, bwl, bwr, bw1);

    scan_buckets_kernel<<<1, 1024, 0, stream>>>(bcnt, bptr, bcur, NB);
    bin_edges_kernel<<<bin_grid, 256, 0, stream>>>(ei, E, bcur, pairs, NB);
    bucket_csr_kernel<<<NB, 256, 0, stream>>>(pairs, bptr, row_ptr, csr_src, NB, N);

    const int gemm_grid = (N + 63) / 64;

    // layer 0 (aggregation fused into the GEMM)
    sage_fused<<<gemm_grid, 256, 0, stream>>>(
        x_bf, row_ptr, csr_src, wl_bf, wr_bf, lin_l_b, lin_r_b, ln_g, ln_b, h1_bf, N);
    // layer 1
    sage_fused<<<gemm_grid, 256, 0, stream>>>(
        h1_bf, row_ptr, csr_src, wl_bf + D * D, wr_bf + D * D, lin_l_b + D, lin_r_b + D,
        ln_g + D, ln_b + D, h2_bf, N);
    // head
    mlp_head_mfma<<<gemm_grid, 256, 0, stream>>>(h2_bf, w1_bf, mlp_b1, mlp_w2, mlp_b2, out, N);
}

// Round 13
// 378.933 us; speedup vs baseline: 1.0773x; 1.0773x over previous
//
#include <hip/hip_runtime.h>
#include <math.h>

#define D 128
#define LN_EPS 1e-5f

#define NB_SHIFT 7                   // 128 nodes per bucket
#define BIN_EPT 16                   // edges per thread in hist/bin passes
#define BIN_CHUNK (BIN_EPT * 256)    // 4096 edges per block
#define MAXB 800                     // >= NB (782)
#define SRC_BITS 25                  // pack: (dloc << 25) | src  (src < 2^25)
#define TS 136                       // out-tile stride (ushorts): rows 16B-aligned

typedef unsigned short ushort_t;
typedef unsigned int uint_t;
typedef __attribute__((ext_vector_type(8))) short bf16x8;
typedef __attribute__((ext_vector_type(8))) unsigned short u16x8;
typedef __attribute__((ext_vector_type(4))) float f32x4;

static __device__ __forceinline__ float bf2f(ushort_t u) {
    union { uint_t i; float f; } c; c.i = ((uint_t)u) << 16; return c.f;
}
static __device__ __forceinline__ ushort_t f2bf(float f) {
    union { float f; uint_t i; } c; c.f = f;
    uint_t u = c.i;
    uint_t r = (u + 0x7fffu + ((u >> 16) & 1u)) >> 16;   // RNE
    return (ushort_t)r;
}

// ---------------- fused prep: 4 bf16 casts + bucket histogram in one launch ---
// Block-range partition: [0,bx) cast x | [bx,bwl) wl | [bwl,bwr) wr |
// [bwr,bw1) w1 | [bw1,...) bucket hist. NT hints ONLY on single-use fp32 reads.
__global__ __launch_bounds__(256) void prep_kernel(
    const float* __restrict__ x, ushort_t* __restrict__ x_bf,
    const float* __restrict__ wl, ushort_t* __restrict__ wl_bf,
    const float* __restrict__ wr, ushort_t* __restrict__ wr_bf,
    const float* __restrict__ w1, ushort_t* __restrict__ w1_bf,
    const int* __restrict__ ei, int E, int* __restrict__ bcnt, int nb,
    int bx, int bwl, int bwr, int bw1) {
    __shared__ int h[MAXB];
    const int b = blockIdx.x;
    const int tid = threadIdx.x;

    if (b < bw1) {
        const float* __restrict__ in;
        ushort_t* __restrict__ outp;
        int rel;
        if (b < bx)       { in = x;  outp = x_bf;  rel = b; }
        else if (b < bwl) { in = wl; outp = wl_bf; rel = b - bx; }
        else if (b < bwr) { in = wr; outp = wr_bf; rel = b - bwl; }
        else              { in = w1; outp = w1_bf; rel = b - bwr; }
        int i = (rel * 256 + tid) * 8;
        f32x4 a = __builtin_nontemporal_load((const f32x4*)&in[i]);
        f32x4 c = __builtin_nontemporal_load((const f32x4*)&in[i + 4]);
        u16x8 v;
        v[0] = f2bf(a.x); v[1] = f2bf(a.y); v[2] = f2bf(a.z); v[3] = f2bf(a.w);
        v[4] = f2bf(c.x); v[5] = f2bf(c.y); v[6] = f2bf(c.z); v[7] = f2bf(c.w);
        *(u16x8*)&outp[i] = v;
        return;
    }

    // bucket histogram branch (cached ei reads — bin_edges re-reads them)
    for (int i = tid; i < nb; i += 256) h[i] = 0;
    __syncthreads();
    int e0 = (b - bw1) * BIN_CHUNK;
    #pragma unroll
    for (int i = 0; i < BIN_EPT; ++i) {
        int e = e0 + i * 256 + tid;
        if (e < E) atomicAdd(&h[ei[E + e] >> NB_SHIFT], 1);
    }
    __syncthreads();
    for (int i = tid; i < nb; i += 256) {
        int c = h[i];
        if (c) atomicAdd(&bcnt[i], c);
    }
}

__global__ __launch_bounds__(1024) void scan_buckets_kernel(const int* __restrict__ bcnt,
                                                            int* __restrict__ bptr,
                                                            int* __restrict__ bcur, int nb) {
    __shared__ int wt[16];
    const int lane = threadIdx.x & 63;
    const int wid = threadIdx.x >> 6;
    int running = 0;
    for (int base = 0; base < nb; base += 1024) {
        int i = base + (int)threadIdx.x;
        int v = (i < nb) ? bcnt[i] : 0;
        int incl = v;
        #pragma unroll
        for (int off = 1; off < 64; off <<= 1) {
            int t = __shfl_up(incl, off, 64);
            if (lane >= off) incl += t;
        }
        if (lane == 63) wt[wid] = incl;
        __syncthreads();
        int prefix = running;
        for (int w = 0; w < wid; ++w) prefix += wt[w];
        if (i < nb) {
            int ex = prefix + incl - v;
            bptr[i] = ex;
            bcur[i] = ex;
        }
        int total = 0;
        for (int w = 0; w < 16; ++w) total += wt[w];
        __syncthreads();
        running += total;
    }
    if (threadIdx.x == 0) bptr[nb] = running;
}

__global__ __launch_bounds__(256) void bin_edges_kernel(const int* __restrict__ ei, int E,
                                                        int* __restrict__ bcur,
                                                        uint_t* __restrict__ pairs, int nb) {
    __shared__ int hist[MAXB];
    __shared__ int base[MAXB];
    const int tid = threadIdx.x;
    for (int i = tid; i < nb; i += 256) hist[i] = 0;
    __syncthreads();

    int e0 = blockIdx.x * BIN_CHUNK;
    int s_r[BIN_EPT], d_r[BIN_EPT], idx_r[BIN_EPT];
    #pragma unroll
    for (int i = 0; i < BIN_EPT; ++i) {
        int e = e0 + i * 256 + tid;
        if (e < E) {
            s_r[i] = ei[e];
            d_r[i] = ei[E + e];
            idx_r[i] = atomicAdd(&hist[d_r[i] >> NB_SHIFT], 1);
        }
    }
    __syncthreads();
    for (int i = tid; i < nb; i += 256) {
        int c = hist[i];
        base[i] = c ? atomicAdd(&bcur[i], c) : 0;
    }
    __syncthreads();
    #pragma unroll
    for (int i = 0; i < BIN_EPT; ++i) {
        int e = e0 + i * 256 + tid;
        if (e < E) {
            int pos = base[d_r[i] >> NB_SHIFT] + idx_r[i];
            pairs[pos] = ((uint_t)(d_r[i] & 127) << SRC_BITS) | (uint_t)s_r[i];
        }
    }
}

__global__ __launch_bounds__(256) void bucket_csr_kernel(const uint_t* __restrict__ pairs,
                                                         const int* __restrict__ bptr,
                                                         int* __restrict__ row_ptr,
                                                         int* __restrict__ csr_src,
                                                         int nb, int n) {
    __shared__ int hist[128];
    __shared__ int cur[128];
    __shared__ int wtot[4];
    const int tid = threadIdx.x;
    const int b = blockIdx.x;
    const int e0 = bptr[b];
    const int e1 = bptr[b + 1];
    const int n0 = b << NB_SHIFT;

    if (tid < 128) hist[tid] = 0;
    __syncthreads();
    for (int e = e0 + tid; e < e1; e += 256)
        atomicAdd(&hist[pairs[e] >> SRC_BITS], 1);
    __syncthreads();

    int v = (tid < 128) ? hist[tid] : 0;
    int lane = tid & 63, wv = tid >> 6;
    int incl = v;
    #pragma unroll
    for (int off = 1; off < 64; off <<= 1) {
        int t = __shfl_up(incl, off, 64);
        if (lane >= off) incl += t;
    }
    if (lane == 63) wtot[wv] = incl;
    __syncthreads();
    if (tid < 128) {
        int excl = incl - v + ((wv == 1) ? wtot[0] : 0);
        cur[tid] = excl;
        int node = n0 + tid;
        if (node < n) row_ptr[node] = e0 + excl;
    }
    if (b == nb - 1 && tid == 0) row_ptr[n] = e1;
    __syncthreads();

    for (int e = e0 + tid; e < e1; e += 256) {
        uint_t p = pairs[e];
        int pos = e0 + atomicAdd(&cur[p >> SRC_BITS], 1);
        csr_src[pos] = (int)(p & ((1u << SRC_BITS) - 1u));
    }
}

// ---------------- fused SAGE layer: gather-agg -> LDS -> MFMA -> LN+SiLU ------
// LDS = exactly 32 KB; overlays after the main K-loop. __launch_bounds__(256,5)
// caps VGPR to 48 — LOAD-BEARING: uncapped (64 VGPR) codegen of the 2x4-chain
// gather loop is 20% slower (R12 evidence). Do not remove.
__global__ __launch_bounds__(256, 5) void sage_fused(
    const ushort_t* __restrict__ hprev,
    const int* __restrict__ row_ptr, const int* __restrict__ csr_src,
    const ushort_t* __restrict__ Wl, const ushort_t* __restrict__ Wr,
    const float* __restrict__ bl, const float* __restrict__ br,
    const float* __restrict__ lng, const float* __restrict__ lnb,
    ushort_t* __restrict__ hout, int n) {
    __shared__ ushort_t stage[16384];          // 32768 B total
    ushort_t* tile = stage;                                        // 64 x TS, 17408 B
    float (*part_s)[4]  = (float(*)[4])((char*)stage + 17408);     // 1 KB
    float (*part_s2)[4] = (float(*)[4])((char*)stage + 18432);     // 1 KB

    const int tid = threadIdx.x;
    const int w = tid >> 6;
    const int lane = tid & 63;
    const int quad = lane >> 4;
    const int l16 = lane & 15;
    const int n0 = blockIdx.x * 64;

    // phase A: stage own hin rows into upper half (chunk-XOR swizzle)
    #pragma unroll
    for (int i = 0; i < 4; ++i) {
        int g = i * 256 + tid;
        int row = g >> 4, ch = g & 15;
        int gr = n0 + row; if (gr >= n) gr = n - 1;
        u16x8 v = *(const u16x8*)&hprev[(size_t)gr * D + ch * 8];
        *(u16x8*)&stage[8192 + row * 128 + (ch ^ (row & 7)) * 8] = v;
    }

    // phase B: aggregation, 2-node interleaved pairs per 16-lane group
    const int G = tid >> 4;
    #pragma unroll
    for (int kp = 0; kp < 2; ++kp) {
        int rowA = G * 4 + kp * 2;
        int rowB = rowA + 1;
        int nodeA = n0 + rowA;
        int nodeB = n0 + rowB;
        float accA[8] = {0.f, 0.f, 0.f, 0.f, 0.f, 0.f, 0.f, 0.f};
        float accB[8] = {0.f, 0.f, 0.f, 0.f, 0.f, 0.f, 0.f, 0.f};
        int eA = 0, s1A = 0, eB = 0, s1B = 0, dgA = 0, dgB = 0;
        if (nodeA < n) { eA = row_ptr[nodeA]; s1A = row_ptr[nodeA + 1]; dgA = s1A - eA; }
        if (nodeB < n) { eB = row_ptr[nodeB]; s1B = row_ptr[nodeB + 1]; dgB = s1B - eB; }
        while (eA + 4 <= s1A && eB + 4 <= s1B) {
            int ia[4], ib[4];
            #pragma unroll
            for (int j = 0; j < 4; ++j) { ia[j] = csr_src[eA + j]; ib[j] = csr_src[eB + j]; }
            u16x8 va[4], vb[4];
            #pragma unroll
            for (int j = 0; j < 4; ++j)
                va[j] = *(const u16x8*)&hprev[(size_t)ia[j] * D + l16 * 8];
            #pragma unroll
            for (int j = 0; j < 4; ++j)
                vb[j] = *(const u16x8*)&hprev[(size_t)ib[j] * D + l16 * 8];
            #pragma unroll
            for (int i = 0; i < 8; ++i) {
                accA[i] += bf2f(va[0][i]) + bf2f(va[1][i]) + bf2f(va[2][i]) + bf2f(va[3][i]);
                accB[i] += bf2f(vb[0][i]) + bf2f(vb[1][i]) + bf2f(vb[2][i]) + bf2f(vb[3][i]);
            }
            eA += 4; eB += 4;
        }
        for (; eA + 4 <= s1A; eA += 4) {
            int ia[4];
            #pragma unroll
            for (int j = 0; j < 4; ++j) ia[j] = csr_src[eA + j];
            u16x8 va[4];
            #pragma unroll
            for (int j = 0; j < 4; ++j)
                va[j] = *(const u16x8*)&hprev[(size_t)ia[j] * D + l16 * 8];
            #pragma unroll
            for (int i = 0; i < 8; ++i)
                accA[i] += bf2f(va[0][i]) + bf2f(va[1][i]) + bf2f(va[2][i]) + bf2f(va[3][i]);
        }
        for (; eA < s1A; ++eA) {
            u16x8 vv = *(const u16x8*)&hprev[(size_t)csr_src[eA] * D + l16 * 8];
            #pragma unroll
            for (int i = 0; i < 8; ++i) accA[i] += bf2f(vv[i]);
        }
        for (; eB + 4 <= s1B; eB += 4) {
            int ib[4];
            #pragma unroll
            for (int j = 0; j < 4; ++j) ib[j] = csr_src[eB + j];
            u16x8 vb[4];
            #pragma unroll
            for (int j = 0; j < 4; ++j)
                vb[j] = *(const u16x8*)&hprev[(size_t)ib[j] * D + l16 * 8];
            #pragma unroll
            for (int i = 0; i < 8; ++i)
                accB[i] += bf2f(vb[0][i]) + bf2f(vb[1][i]) + bf2f(vb[2][i]) + bf2f(vb[3][i]);
        }
        for (; eB < s1B; ++eB) {
            u16x8 vv = *(const u16x8*)&hprev[(size_t)csr_src[eB] * D + l16 * 8];
            #pragma unroll
            for (int i = 0; i < 8; ++i) accB[i] += bf2f(vv[i]);
        }
        float scA = (dgA > 0) ? (1.0f / (float)dgA) : 0.0f;
        float scB = (dgB > 0) ? (1.0f / (float)dgB) : 0.0f;
        u16x8 oA, oB;
        #pragma unroll
        for (int i = 0; i < 8; ++i) { oA[i] = f2bf(accA[i] * scA); oB[i] = f2bf(accB[i] * scB); }
        *(u16x8*)&stage[rowA * 128 + (l16 ^ (rowA & 7)) * 8] = oA;
        *(u16x8*)&stage[rowB * 128 + (l16 ^ (rowB & 7)) * 8] = oB;
    }
    __syncthreads();

    // phase C: main K=256 MFMA (A from LDS, B from global/L2)
    f32x4 acc[4][2];
    #pragma unroll
    for (int rt = 0; rt < 4; ++rt)
        #pragma unroll
        for (int jl = 0; jl < 2; ++jl) acc[rt][jl] = (f32x4){0.f, 0.f, 0.f, 0.f};

    #pragma unroll
    for (int c = 0; c < 8; ++c) {
        const ushort_t* __restrict__ W = (c < 4) ? Wl : Wr;
        const int kb = (c & 3) * 32;
        const ushort_t* sbase = &stage[(c < 4) ? 0 : 8192];
        const int cl = (c & 3) * 4 + quad;
        bf16x8 bfr[2];
        #pragma unroll
        for (int jl = 0; jl < 2; ++jl) {
            int j = (2 * w + jl) * 16 + l16;
            bfr[jl] = *(const bf16x8*)&W[(size_t)j * D + kb + quad * 8];
        }
        bf16x8 af[4];
        #pragma unroll
        for (int rt = 0; rt < 4; ++rt) {
            int row = rt * 16 + l16;
            af[rt] = *(const bf16x8*)&sbase[row * 128 + ((cl ^ (l16 & 7)) * 8)];
        }
        #pragma unroll
        for (int rt = 0; rt < 4; ++rt)
            #pragma unroll
            for (int jl = 0; jl < 2; ++jl)
                acc[rt][jl] = __builtin_amdgcn_mfma_f32_16x16x32_bf16(af[rt], bfr[jl],
                                                                      acc[rt][jl], 0, 0, 0);
    }
    __syncthreads();   // stage reads done; overlays become writable

    // phase D: bias + cross-wave LN partials
    float bsum[2], g[2], bb[2];
    #pragma unroll
    for (int jl = 0; jl < 2; ++jl) {
        int j = (2 * w + jl) * 16 + l16;
        bsum[jl] = bl[j] + br[j];
        g[jl] = lng[j];
        bb[jl] = lnb[j];
    }
    #pragma unroll
    for (int rt = 0; rt < 4; ++rt) {
        #pragma unroll
        for (int r = 0; r < 4; ++r) {
            float v0 = acc[rt][0][r] + bsum[0];
            float v1 = acc[rt][1][r] + bsum[1];
            acc[rt][0][r] = v0;
            acc[rt][1][r] = v1;
            float s = v0 + v1;
            float s2 = v0 * v0 + v1 * v1;
            #pragma unroll
            for (int off = 1; off < 16; off <<= 1) {
                s += __shfl_xor(s, off, 64);
                s2 += __shfl_xor(s2, off, 64);
            }
            if (l16 == 0) {
                int row = rt * 16 + quad * 4 + r;
                part_s[row][w] = s;
                part_s2[row][w] = s2;
            }
        }
    }
    __syncthreads();

    // finish LN + SiLU, write bf16 out-tile
    #pragma unroll
    for (int rt = 0; rt < 4; ++rt) {
        #pragma unroll
        for (int r = 0; r < 4; ++r) {
            int row = rt * 16 + quad * 4 + r;
            float s = part_s[row][0] + part_s[row][1] + part_s[row][2] + part_s[row][3];
            float s2 = part_s2[row][0] + part_s2[row][1] + part_s2[row][2] + part_s2[row][3];
            float mean = s * (1.0f / 128.0f);
            float var = s2 * (1.0f / 128.0f) - mean * mean;
            float rstd = rsqrtf(var + LN_EPS);
            #pragma unroll
            for (int jl = 0; jl < 2; ++jl) {
                float z = (acc[rt][jl][r] - mean) * rstd * g[jl] + bb[jl];
                float sv = z / (1.0f + expf(-z));
                tile[row * TS + (2 * w + jl) * 16 + l16] = f2bf(sv);
            }
        }
    }
    __syncthreads();
    int row = tid >> 2, seg = tid & 3;
    int node = n0 + row;
    if (node < n) {
        #pragma unroll
        for (int k2 = 0; k2 < 4; ++k2) {
            u16x8 vv = *(const u16x8*)&tile[row * TS + seg * 32 + k2 * 8];
            *(u16x8*)&hout[(size_t)node * D + seg * 32 + k2 * 8] = vv;
        }
    }
}

// ---------------- fused MLP head: LDS-staged A + MFMA + ReLU + dot(w2) -------
__global__ __launch_bounds__(256) void mlp_head_mfma(
    const ushort_t* __restrict__ hin, const ushort_t* __restrict__ W1,
    const float* __restrict__ b1, const float* __restrict__ w2,
    const float* __restrict__ b2, float* __restrict__ out, int n) {
    __shared__ ushort_t stage[64 * 128];
    __shared__ float part[64][4];

    const int tid = threadIdx.x;
    const int w = tid >> 6;
    const int lane = tid & 63;
    const int quad = lane >> 4;
    const int l16 = lane & 15;
    const int n0 = blockIdx.x * 64;

    #pragma unroll
    for (int i = 0; i < 4; ++i) {
        int g = i * 256 + tid;
        int row = g >> 4, ch = g & 15;
        int gr = n0 + row; if (gr >= n) gr = n - 1;
        u16x8 v = *(const u16x8*)&hin[(size_t)gr * D + ch * 8];
        *(u16x8*)&stage[row * 128 + (ch ^ (row & 7)) * 8] = v;
    }
    __syncthreads();

    f32x4 acc[4][2];
    #pragma unroll
    for (int rt = 0; rt < 4; ++rt)
        #pragma unroll
        for (int jl = 0; jl < 2; ++jl) acc[rt][jl] = (f32x4){0.f, 0.f, 0.f, 0.f};

    #pragma unroll
    for (int c = 0; c < 4; ++c) {
        const int kb = c * 32;
        const int cl = c * 4 + quad;
        bf16x8 bfr[2];
        #pragma unroll
        for (int jl = 0; jl < 2; ++jl) {
            int j = (2 * w + jl) * 16 + l16;
            bfr[jl] = *(const bf16x8*)&W1[(size_t)j * D + kb + quad * 8];
        }
        bf16x8 af[4];
        #pragma unroll
        for (int rt = 0; rt < 4; ++rt) {
            int row = rt * 16 + l16;
            af[rt] = *(const bf16x8*)&stage[row * 128 + ((cl ^ (l16 & 7)) * 8)];
        }
        #pragma unroll
        for (int rt = 0; rt < 4; ++rt)
            #pragma unroll
            for (int jl = 0; jl < 2; ++jl)
                acc[rt][jl] = __builtin_amdgcn_mfma_f32_16x16x32_bf16(af[rt], bfr[jl],
                                                                      acc[rt][jl], 0, 0, 0);
    }

    float bias1[2], wv2[2];
    #pragma unroll
    for (int jl = 0; jl < 2; ++jl) {
        int j = (2 * w + jl) * 16 + l16;
        bias1[jl] = b1[j];
        wv2[jl] = w2[j];
    }
    #pragma unroll
    for (int rt = 0; rt < 4; ++rt) {
        #pragma unroll
        for (int r = 0; r < 4; ++r) {
            float p = fmaxf(acc[rt][0][r] + bias1[0], 0.0f) * wv2[0]
                    + fmaxf(acc[rt][1][r] + bias1[1], 0.0f) * wv2[1];
            #pragma unroll
            for (int off = 1; off < 16; off <<= 1) p += __shfl_xor(p, off, 64);
            if (l16 == 0) part[rt * 16 + quad * 4 + r][w] = p;
        }
    }
    __syncthreads();
    if (tid < 64) {
        int node = n0 + tid;
        if (node < n)
            out[node] = part[tid][0] + part[tid][1] + part[tid][2] + part[tid][3] + b2[0];
    }
}

// ---------------- launch ----------------
static inline size_t align_up(size_t v, size_t a) { return (v + a - 1) & ~(a - 1); }

extern "C" void kernel_launch(void* const* d_in, const int* in_sizes, int n_in,
                              void* d_out, int out_size, void* d_ws, size_t ws_size,
                              hipStream_t stream) {
    const float* x       = (const float*)d_in[0];
    const int*   ei      = (const int*)d_in[1];
    const float* lin_l_w = (const float*)d_in[2];
    const float* lin_l_b = (const float*)d_in[3];
    const float* lin_r_w = (const float*)d_in[4];
    const float* lin_r_b = (const float*)d_in[5];
    const float* ln_g    = (const float*)d_in[6];
    const float* ln_b    = (const float*)d_in[7];
    const float* mlp_w1  = (const float*)d_in[8];
    const float* mlp_b1  = (const float*)d_in[9];
    const float* mlp_w2  = (const float*)d_in[10];
    const float* mlp_b2  = (const float*)d_in[11];
    float* out = (float*)d_out;

    const int N = in_sizes[0] / D;   // 100000
    const int E = in_sizes[1] / 2;   // 1600000
    const int NB = (N + (1 << NB_SHIFT) - 1) >> NB_SHIFT;   // 782

    // workspace layout
    char* w = (char*)d_ws;
    size_t off = 0;
    int* bcnt = (int*)(w + off);       off = align_up(off + sizeof(int) * (size_t)(NB + 1), 512);
    int* bptr = (int*)(w + off);       off = align_up(off + sizeof(int) * (size_t)(NB + 1), 512);
    int* bcur = (int*)(w + off);       off = align_up(off + sizeof(int) * (size_t)(NB + 1), 512);
    int* row_ptr = (int*)(w + off);    off = align_up(off + sizeof(int) * (size_t)(N + 1), 512);
    int* csr_src = (int*)(w + off);    off = align_up(off + sizeof(int) * (size_t)E, 512);
    uint_t* pairs = (uint_t*)(w + off); off = align_up(off + sizeof(uint_t) * (size_t)E, 512);
    ushort_t* x_bf = (ushort_t*)(w + off);   off = align_up(off + 2ull * N * D, 512);
    ushort_t* h1_bf = (ushort_t*)(w + off);  off = align_up(off + 2ull * N * D, 512);
    ushort_t* h2_bf = (ushort_t*)(w + off);  off = align_up(off + 2ull * N * D, 512);
    ushort_t* wl_bf = (ushort_t*)(w + off);  off = align_up(off + 2ull * 2 * D * D, 512);
    ushort_t* wr_bf = (ushort_t*)(w + off);  off = align_up(off + 2ull * 2 * D * D, 512);
    ushort_t* w1_bf = (ushort_t*)(w + off);  off = align_up(off + 2ull * D * D, 512);

    hipMemsetAsync(bcnt, 0, sizeof(int) * (size_t)(NB + 1), stream);

    // fused prep: x/wl/wr/w1 casts + bucket histogram (one launch)
    const int bx  = (N * D) / 2048;              // 6250
    const int bwl = bx + (2 * D * D) / 2048;     // +16
    const int bwr = bwl + (2 * D * D) / 2048;    // +16
    const int bw1 = bwr + (D * D) / 2048;        // +8
    const int bin_grid = (E + BIN_CHUNK - 1) / BIN_CHUNK;   // 391
    prep_kernel<<<bw1 + bin_grid, 256, 0, stream>>>(
        x, x_bf, lin_l_w, wl_bf, lin_r_w, wr_bf, mlp_w1, w1_bf,
        ei, E, bcnt, NB, bx, bwl, bwr, bw1);

    scan_buckets_kernel<<<1, 1024, 0, stream>>>(bcnt, bptr, bcur, NB);
    bin_edges_kernel<<<bin_grid, 256, 0, stream>>>(ei, E, bcur, pairs, NB);
    bucket_csr_kernel<<<NB, 256, 0, stream>>>(pairs, bptr, row_ptr, csr_src, NB, N);

    const int gemm_grid = (N + 63) / 64;

    // layer 0 (aggregation fused into the GEMM)
    sage_fused<<<gemm_grid, 256, 0, stream>>>(
        x_bf, row_ptr, csr_src, wl_bf, wr_bf, lin_l_b, lin_r_b, ln_g, ln_b, h1_bf, N);
    // layer 1
    sage_fused<<<gemm_grid, 256, 0, stream>>>(
        h1_bf, row_ptr, csr_src, wl_bf + D * D, wr_bf + D * D, lin_l_b + D, lin_r_b + D,
        ln_g + D, ln_b + D, h2_bf, N);
    // head
    mlp_head_mfma<<<gemm_grid, 256, 0, stream>>>(h2_bf, w1_bf, mlp_b1, mlp_w2, mlp_b2, out, N);
}

// Round 14
// 375.443 us; speedup vs baseline: 1.0874x; 1.0093x over previous
//
#include <hip/hip_runtime.h>
#include <math.h>

#define D 128
#define LN_EPS 1e-5f

#define NB_SHIFT 7                   // 128 nodes per bucket
#define BIN_EPT 16                   // edges per thread in hist/bin passes
#define BIN_CHUNK (BIN_EPT * 256)    // 4096 edges per block
#define MAXB 800                     // >= NB (782)
#define SRC_BITS 25                  // pack: (dloc << 25) | src  (src < 2^25)
#define TS 136                       // out-tile stride (ushorts): rows 16B-aligned

typedef unsigned short ushort_t;
typedef unsigned int uint_t;
typedef __attribute__((ext_vector_type(8))) short bf16x8;
typedef __attribute__((ext_vector_type(8))) unsigned short u16x8;
typedef __attribute__((ext_vector_type(4))) float f32x4;

static __device__ __forceinline__ float bf2f(ushort_t u) {
    union { uint_t i; float f; } c; c.i = ((uint_t)u) << 16; return c.f;
}
static __device__ __forceinline__ ushort_t f2bf(float f) {
    union { float f; uint_t i; } c; c.f = f;
    uint_t u = c.i;
    uint_t r = (u + 0x7fffu + ((u >> 16) & 1u)) >> 16;   // RNE
    return (ushort_t)r;
}

// cast 2048 fp32 -> bf16 for block-relative index `rel` (no tail: counts are
// multiples of 2048). NT on the single-use fp32 reads only.
static __device__ __forceinline__ void cast_block(const float* __restrict__ in,
                                                  ushort_t* __restrict__ outp,
                                                  int rel, int tid) {
    int i = (rel * 256 + tid) * 8;
    f32x4 a = __builtin_nontemporal_load((const f32x4*)&in[i]);
    f32x4 c = __builtin_nontemporal_load((const f32x4*)&in[i + 4]);
    u16x8 v;
    v[0] = f2bf(a.x); v[1] = f2bf(a.y); v[2] = f2bf(a.z); v[3] = f2bf(a.w);
    v[4] = f2bf(c.x); v[5] = f2bf(c.y); v[6] = f2bf(c.z); v[7] = f2bf(c.w);
    *(u16x8*)&outp[i] = v;
}

// ---------------- prep: weight casts + bucket histogram (one launch) ---------
// [0,bwl) wl | [bwl,bwr) wr | [bwr,bw1) w1 | [bw1,...) bucket hist
__global__ __launch_bounds__(256) void prep_kernel(
    const float* __restrict__ wl, ushort_t* __restrict__ wl_bf,
    const float* __restrict__ wr, ushort_t* __restrict__ wr_bf,
    const float* __restrict__ w1, ushort_t* __restrict__ w1_bf,
    const int* __restrict__ ei, int E, int* __restrict__ bcnt, int nb,
    int bwl, int bwr, int bw1) {
    __shared__ int h[MAXB];
    const int b = blockIdx.x;
    const int tid = threadIdx.x;

    if (b < bw1) {
        if (b < bwl)      cast_block(wl, wl_bf, b, tid);
        else if (b < bwr) cast_block(wr, wr_bf, b - bwl, tid);
        else              cast_block(w1, w1_bf, b - bwr, tid);
        return;
    }

    // bucket histogram branch (cached ei reads — bin_edges re-reads them)
    for (int i = tid; i < nb; i += 256) h[i] = 0;
    __syncthreads();
    int e0 = (b - bw1) * BIN_CHUNK;
    #pragma unroll
    for (int i = 0; i < BIN_EPT; ++i) {
        int e = e0 + i * 256 + tid;
        if (e < E) atomicAdd(&h[ei[E + e] >> NB_SHIFT], 1);
    }
    __syncthreads();
    for (int i = tid; i < nb; i += 256) {
        int c = h[i];
        if (c) atomicAdd(&bcnt[i], c);
    }
}

__global__ __launch_bounds__(1024) void scan_buckets_kernel(const int* __restrict__ bcnt,
                                                            int* __restrict__ bptr,
                                                            int* __restrict__ bcur, int nb) {
    __shared__ int wt[16];
    const int lane = threadIdx.x & 63;
    const int wid = threadIdx.x >> 6;
    int running = 0;
    for (int base = 0; base < nb; base += 1024) {
        int i = base + (int)threadIdx.x;
        int v = (i < nb) ? bcnt[i] : 0;
        int incl = v;
        #pragma unroll
        for (int off = 1; off < 64; off <<= 1) {
            int t = __shfl_up(incl, off, 64);
            if (lane >= off) incl += t;
        }
        if (lane == 63) wt[wid] = incl;
        __syncthreads();
        int prefix = running;
        for (int w = 0; w < wid; ++w) prefix += wt[w];
        if (i < nb) {
            int ex = prefix + incl - v;
            bptr[i] = ex;
            bcur[i] = ex;
        }
        int total = 0;
        for (int w = 0; w < 16; ++w) total += wt[w];
        __syncthreads();
        running += total;
    }
    if (threadIdx.x == 0) bptr[nb] = running;
}

// ---------------- bin pass + x cast fused (machine-fill during binning) ------
// [0,bx) cast x | [bx,...) scatter packed (dloc<<25|src) into bucket regions
__global__ __launch_bounds__(256) void bin_edges_kernel(
    const float* __restrict__ x, ushort_t* __restrict__ x_bf,
    const int* __restrict__ ei, int E,
    int* __restrict__ bcur, uint_t* __restrict__ pairs, int nb, int bx) {
    __shared__ int hist[MAXB];
    __shared__ int base[MAXB];
    const int b = blockIdx.x;
    const int tid = threadIdx.x;

    if (b < bx) { cast_block(x, x_bf, b, tid); return; }

    for (int i = tid; i < nb; i += 256) hist[i] = 0;
    __syncthreads();

    int e0 = (b - bx) * BIN_CHUNK;
    int s_r[BIN_EPT], d_r[BIN_EPT], idx_r[BIN_EPT];
    #pragma unroll
    for (int i = 0; i < BIN_EPT; ++i) {
        int e = e0 + i * 256 + tid;
        if (e < E) {
            s_r[i] = ei[e];
            d_r[i] = ei[E + e];
            idx_r[i] = atomicAdd(&hist[d_r[i] >> NB_SHIFT], 1);
        }
    }
    __syncthreads();
    for (int i = tid; i < nb; i += 256) {
        int c = hist[i];
        base[i] = c ? atomicAdd(&bcur[i], c) : 0;
    }
    __syncthreads();
    #pragma unroll
    for (int i = 0; i < BIN_EPT; ++i) {
        int e = e0 + i * 256 + tid;
        if (e < E) {
            int pos = base[d_r[i] >> NB_SHIFT] + idx_r[i];
            pairs[pos] = ((uint_t)(d_r[i] & 127) << SRC_BITS) | (uint_t)s_r[i];
        }
    }
}

__global__ __launch_bounds__(256) void bucket_csr_kernel(const uint_t* __restrict__ pairs,
                                                         const int* __restrict__ bptr,
                                                         int* __restrict__ row_ptr,
                                                         int* __restrict__ csr_src,
                                                         int nb, int n) {
    __shared__ int hist[128];
    __shared__ int cur[128];
    __shared__ int wtot[4];
    const int tid = threadIdx.x;
    const int b = blockIdx.x;
    const int e0 = bptr[b];
    const int e1 = bptr[b + 1];
    const int n0 = b << NB_SHIFT;

    if (tid < 128) hist[tid] = 0;
    __syncthreads();
    for (int e = e0 + tid; e < e1; e += 256)
        atomicAdd(&hist[pairs[e] >> SRC_BITS], 1);
    __syncthreads();

    int v = (tid < 128) ? hist[tid] : 0;
    int lane = tid & 63, wv = tid >> 6;
    int incl = v;
    #pragma unroll
    for (int off = 1; off < 64; off <<= 1) {
        int t = __shfl_up(incl, off, 64);
        if (lane >= off) incl += t;
    }
    if (lane == 63) wtot[wv] = incl;
    __syncthreads();
    if (tid < 128) {
        int excl = incl - v + ((wv == 1) ? wtot[0] : 0);
        cur[tid] = excl;
        int node = n0 + tid;
        if (node < n) row_ptr[node] = e0 + excl;
    }
    if (b == nb - 1 && tid == 0) row_ptr[n] = e1;
    __syncthreads();

    for (int e = e0 + tid; e < e1; e += 256) {
        uint_t p = pairs[e];
        int pos = e0 + atomicAdd(&cur[p >> SRC_BITS], 1);
        csr_src[pos] = (int)(p & ((1u << SRC_BITS) - 1u));
    }
}

// ---------------- fused SAGE layer: gather-agg -> LDS -> MFMA -> LN+SiLU ------
// LDS = exactly 32 KB; overlays after the main K-loop. Per-dispatch duration
// varies 102-125 us across sessions at fixed source (run/clock variance, R13).
__global__ __launch_bounds__(256, 5) void sage_fused(
    const ushort_t* __restrict__ hprev,
    const int* __restrict__ row_ptr, const int* __restrict__ csr_src,
    const ushort_t* __restrict__ Wl, const ushort_t* __restrict__ Wr,
    const float* __restrict__ bl, const float* __restrict__ br,
    const float* __restrict__ lng, const float* __restrict__ lnb,
    ushort_t* __restrict__ hout, int n) {
    __shared__ ushort_t stage[16384];          // 32768 B total
    ushort_t* tile = stage;                                        // 64 x TS, 17408 B
    float (*part_s)[4]  = (float(*)[4])((char*)stage + 17408);     // 1 KB
    float (*part_s2)[4] = (float(*)[4])((char*)stage + 18432);     // 1 KB

    const int tid = threadIdx.x;
    const int w = tid >> 6;
    const int lane = tid & 63;
    const int quad = lane >> 4;
    const int l16 = lane & 15;
    const int n0 = blockIdx.x * 64;

    // phase A: stage own hin rows into upper half (chunk-XOR swizzle)
    #pragma unroll
    for (int i = 0; i < 4; ++i) {
        int g = i * 256 + tid;
        int row = g >> 4, ch = g & 15;
        int gr = n0 + row; if (gr >= n) gr = n - 1;
        u16x8 v = *(const u16x8*)&hprev[(size_t)gr * D + ch * 8];
        *(u16x8*)&stage[8192 + row * 128 + (ch ^ (row & 7)) * 8] = v;
    }

    // phase B: aggregation, 2-node interleaved pairs per 16-lane group
    const int G = tid >> 4;
    #pragma unroll
    for (int kp = 0; kp < 2; ++kp) {
        int rowA = G * 4 + kp * 2;
        int rowB = rowA + 1;
        int nodeA = n0 + rowA;
        int nodeB = n0 + rowB;
        float accA[8] = {0.f, 0.f, 0.f, 0.f, 0.f, 0.f, 0.f, 0.f};
        float accB[8] = {0.f, 0.f, 0.f, 0.f, 0.f, 0.f, 0.f, 0.f};
        int eA = 0, s1A = 0, eB = 0, s1B = 0, dgA = 0, dgB = 0;
        if (nodeA < n) { eA = row_ptr[nodeA]; s1A = row_ptr[nodeA + 1]; dgA = s1A - eA; }
        if (nodeB < n) { eB = row_ptr[nodeB]; s1B = row_ptr[nodeB + 1]; dgB = s1B - eB; }
        while (eA + 4 <= s1A && eB + 4 <= s1B) {
            int ia[4], ib[4];
            #pragma unroll
            for (int j = 0; j < 4; ++j) { ia[j] = csr_src[eA + j]; ib[j] = csr_src[eB + j]; }
            u16x8 va[4], vb[4];
            #pragma unroll
            for (int j = 0; j < 4; ++j)
                va[j] = *(const u16x8*)&hprev[(size_t)ia[j] * D + l16 * 8];
            #pragma unroll
            for (int j = 0; j < 4; ++j)
                vb[j] = *(const u16x8*)&hprev[(size_t)ib[j] * D + l16 * 8];
            #pragma unroll
            for (int i = 0; i < 8; ++i) {
                accA[i] += bf2f(va[0][i]) + bf2f(va[1][i]) + bf2f(va[2][i]) + bf2f(va[3][i]);
                accB[i] += bf2f(vb[0][i]) + bf2f(vb[1][i]) + bf2f(vb[2][i]) + bf2f(vb[3][i]);
            }
            eA += 4; eB += 4;
        }
        for (; eA + 4 <= s1A; eA += 4) {
            int ia[4];
            #pragma unroll
            for (int j = 0; j < 4; ++j) ia[j] = csr_src[eA + j];
            u16x8 va[4];
            #pragma unroll
            for (int j = 0; j < 4; ++j)
                va[j] = *(const u16x8*)&hprev[(size_t)ia[j] * D + l16 * 8];
            #pragma unroll
            for (int i = 0; i < 8; ++i)
                accA[i] += bf2f(va[0][i]) + bf2f(va[1][i]) + bf2f(va[2][i]) + bf2f(va[3][i]);
        }
        for (; eA < s1A; ++eA) {
            u16x8 vv = *(const u16x8*)&hprev[(size_t)csr_src[eA] * D + l16 * 8];
            #pragma unroll
            for (int i = 0; i < 8; ++i) accA[i] += bf2f(vv[i]);
        }
        for (; eB + 4 <= s1B; eB += 4) {
            int ib[4];
            #pragma unroll
            for (int j = 0; j < 4; ++j) ib[j] = csr_src[eB + j];
            u16x8 vb[4];
            #pragma unroll
            for (int j = 0; j < 4; ++j)
                vb[j] = *(const u16x8*)&hprev[(size_t)ib[j] * D + l16 * 8];
            #pragma unroll
            for (int i = 0; i < 8; ++i)
                accB[i] += bf2f(vb[0][i]) + bf2f(vb[1][i]) + bf2f(vb[2][i]) + bf2f(vb[3][i]);
        }
        for (; eB < s1B; ++eB) {
            u16x8 vv = *(const u16x8*)&hprev[(size_t)csr_src[eB] * D + l16 * 8];
            #pragma unroll
            for (int i = 0; i < 8; ++i) accB[i] += bf2f(vv[i]);
        }
        float scA = (dgA > 0) ? (1.0f / (float)dgA) : 0.0f;
        float scB = (dgB > 0) ? (1.0f / (float)dgB) : 0.0f;
        u16x8 oA, oB;
        #pragma unroll
        for (int i = 0; i < 8; ++i) { oA[i] = f2bf(accA[i] * scA); oB[i] = f2bf(accB[i] * scB); }
        *(u16x8*)&stage[rowA * 128 + (l16 ^ (rowA & 7)) * 8] = oA;
        *(u16x8*)&stage[rowB * 128 + (l16 ^ (rowB & 7)) * 8] = oB;
    }
    __syncthreads();

    // phase C: main K=256 MFMA (A from LDS, B from global/L2)
    f32x4 acc[4][2];
    #pragma unroll
    for (int rt = 0; rt < 4; ++rt)
        #pragma unroll
        for (int jl = 0; jl < 2; ++jl) acc[rt][jl] = (f32x4){0.f, 0.f, 0.f, 0.f};

    #pragma unroll
    for (int c = 0; c < 8; ++c) {
        const ushort_t* __restrict__ W = (c < 4) ? Wl : Wr;
        const int kb = (c & 3) * 32;
        const ushort_t* sbase = &stage[(c < 4) ? 0 : 8192];
        const int cl = (c & 3) * 4 + quad;
        bf16x8 bfr[2];
        #pragma unroll
        for (int jl = 0; jl < 2; ++jl) {
            int j = (2 * w + jl) * 16 + l16;
            bfr[jl] = *(const bf16x8*)&W[(size_t)j * D + kb + quad * 8];
        }
        bf16x8 af[4];
        #pragma unroll
        for (int rt = 0; rt < 4; ++rt) {
            int row = rt * 16 + l16;
            af[rt] = *(const bf16x8*)&sbase[row * 128 + ((cl ^ (l16 & 7)) * 8)];
        }
        #pragma unroll
        for (int rt = 0; rt < 4; ++rt)
            #pragma unroll
            for (int jl = 0; jl < 2; ++jl)
                acc[rt][jl] = __builtin_amdgcn_mfma_f32_16x16x32_bf16(af[rt], bfr[jl],
                                                                      acc[rt][jl], 0, 0, 0);
    }
    __syncthreads();   // stage reads done; overlays become writable

    // phase D: bias + cross-wave LN partials
    float bsum[2], g[2], bb[2];
    #pragma unroll
    for (int jl = 0; jl < 2; ++jl) {
        int j = (2 * w + jl) * 16 + l16;
        bsum[jl] = bl[j] + br[j];
        g[jl] = lng[j];
        bb[jl] = lnb[j];
    }
    #pragma unroll
    for (int rt = 0; rt < 4; ++rt) {
        #pragma unroll
        for (int r = 0; r < 4; ++r) {
            float v0 = acc[rt][0][r] + bsum[0];
            float v1 = acc[rt][1][r] + bsum[1];
            acc[rt][0][r] = v0;
            acc[rt][1][r] = v1;
            float s = v0 + v1;
            float s2 = v0 * v0 + v1 * v1;
            #pragma unroll
            for (int off = 1; off < 16; off <<= 1) {
                s += __shfl_xor(s, off, 64);
                s2 += __shfl_xor(s2, off, 64);
            }
            if (l16 == 0) {
                int row = rt * 16 + quad * 4 + r;
                part_s[row][w] = s;
                part_s2[row][w] = s2;
            }
        }
    }
    __syncthreads();

    // finish LN + SiLU, write bf16 out-tile
    #pragma unroll
    for (int rt = 0; rt < 4; ++rt) {
        #pragma unroll
        for (int r = 0; r < 4; ++r) {
            int row = rt * 16 + quad * 4 + r;
            float s = part_s[row][0] + part_s[row][1] + part_s[row][2] + part_s[row][3];
            float s2 = part_s2[row][0] + part_s2[row][1] + part_s2[row][2] + part_s2[row][3];
            float mean = s * (1.0f / 128.0f);
            float var = s2 * (1.0f / 128.0f) - mean * mean;
            float rstd = rsqrtf(var + LN_EPS);
            #pragma unroll
            for (int jl = 0; jl < 2; ++jl) {
                float z = (acc[rt][jl][r] - mean) * rstd * g[jl] + bb[jl];
                float sv = z / (1.0f + expf(-z));
                tile[row * TS + (2 * w + jl) * 16 + l16] = f2bf(sv);
            }
        }
    }
    __syncthreads();
    int row = tid >> 2, seg = tid & 3;
    int node = n0 + row;
    if (node < n) {
        #pragma unroll
        for (int k2 = 0; k2 < 4; ++k2) {
            u16x8 vv = *(const u16x8*)&tile[row * TS + seg * 32 + k2 * 8];
            *(u16x8*)&hout[(size_t)node * D + seg * 32 + k2 * 8] = vv;
        }
    }
}

// ---------------- fused MLP head: LDS-staged A + MFMA + ReLU + dot(w2) -------
__global__ __launch_bounds__(256) void mlp_head_mfma(
    const ushort_t* __restrict__ hin, const ushort_t* __restrict__ W1,
    const float* __restrict__ b1, const float* __restrict__ w2,
    const float* __restrict__ b2, float* __restrict__ out, int n) {
    __shared__ ushort_t stage[64 * 128];
    __shared__ float part[64][4];

    const int tid = threadIdx.x;
    const int w = tid >> 6;
    const int lane = tid & 63;
    const int quad = lane >> 4;
    const int l16 = lane & 15;
    const int n0 = blockIdx.x * 64;

    #pragma unroll
    for (int i = 0; i < 4; ++i) {
        int g = i * 256 + tid;
        int row = g >> 4, ch = g & 15;
        int gr = n0 + row; if (gr >= n) gr = n - 1;
        u16x8 v = *(const u16x8*)&hin[(size_t)gr * D + ch * 8];
        *(u16x8*)&stage[row * 128 + (ch ^ (row & 7)) * 8] = v;
    }
    __syncthreads();

    f32x4 acc[4][2];
    #pragma unroll
    for (int rt = 0; rt < 4; ++rt)
        #pragma unroll
        for (int jl = 0; jl < 2; ++jl) acc[rt][jl] = (f32x4){0.f, 0.f, 0.f, 0.f};

    #pragma unroll
    for (int c = 0; c < 4; ++c) {
        const int kb = c * 32;
        const int cl = c * 4 + quad;
        bf16x8 bfr[2];
        #pragma unroll
        for (int jl = 0; jl < 2; ++jl) {
            int j = (2 * w + jl) * 16 + l16;
            bfr[jl] = *(const bf16x8*)&W1[(size_t)j * D + kb + quad * 8];
        }
        bf16x8 af[4];
        #pragma unroll
        for (int rt = 0; rt < 4; ++rt) {
            int row = rt * 16 + l16;
            af[rt] = *(const bf16x8*)&stage[row * 128 + ((cl ^ (l16 & 7)) * 8)];
        }
        #pragma unroll
        for (int rt = 0; rt < 4; ++rt)
            #pragma unroll
            for (int jl = 0; jl < 2; ++jl)
                acc[rt][jl] = __builtin_amdgcn_mfma_f32_16x16x32_bf16(af[rt], bfr[jl],
                                                                      acc[rt][jl], 0, 0, 0);
    }

    float bias1[2], wv2[2];
    #pragma unroll
    for (int jl = 0; jl < 2; ++jl) {
        int j = (2 * w + jl) * 16 + l16;
        bias1[jl] = b1[j];
        wv2[jl] = w2[j];
    }
    #pragma unroll
    for (int rt = 0; rt < 4; ++rt) {
        #pragma unroll
        for (int r = 0; r < 4; ++r) {
            float p = fmaxf(acc[rt][0][r] + bias1[0], 0.0f) * wv2[0]
                    + fmaxf(acc[rt][1][r] + bias1[1], 0.0f) * wv2[1];
            #pragma unroll
            for (int off = 1; off < 16; off <<= 1) p += __shfl_xor(p, off, 64);
            if (l16 == 0) part[rt * 16 + quad * 4 + r][w] = p;
        }
    }
    __syncthreads();
    if (tid < 64) {
        int node = n0 + tid;
        if (node < n)
            out[node] = part[tid][0] + part[tid][1] + part[tid][2] + part[tid][3] + b2[0];
    }
}

// ---------------- launch ----------------
static inline size_t align_up(size_t v, size_t a) { return (v + a - 1) & ~(a - 1); }

extern "C" void kernel_launch(void* const* d_in, const int* in_sizes, int n_in,
                              void* d_out, int out_size, void* d_ws, size_t ws_size,
                              hipStream_t stream) {
    const float* x       = (const float*)d_in[0];
    const int*   ei      = (const int*)d_in[1];
    const float* lin_l_w = (const float*)d_in[2];
    const float* lin_l_b = (const float*)d_in[3];
    const float* lin_r_w = (const float*)d_in[4];
    const float* lin_r_b = (const float*)d_in[5];
    const float* ln_g    = (const float*)d_in[6];
    const float* ln_b    = (const float*)d_in[7];
    const float* mlp_w1  = (const float*)d_in[8];
    const float* mlp_b1  = (const float*)d_in[9];
    const float* mlp_w2  = (const float*)d_in[10];
    const float* mlp_b2  = (const float*)d_in[11];
    float* out = (float*)d_out;

    const int N = in_sizes[0] / D;   // 100000
    const int E = in_sizes[1] / 2;   // 1600000
    const int NB = (N + (1 << NB_SHIFT) - 1) >> NB_SHIFT;   // 782

    // workspace layout
    char* w = (char*)d_ws;
    size_t off = 0;
    int* bcnt = (int*)(w + off);       off = align_up(off + sizeof(int) * (size_t)(NB + 1), 512);
    int* bptr = (int*)(w + off);       off = align_up(off + sizeof(int) * (size_t)(NB + 1), 512);
    int* bcur = (int*)(w + off);       off = align_up(off + sizeof(int) * (size_t)(NB + 1), 512);
    int* row_ptr = (int*)(w + off);    off = align_up(off + sizeof(int) * (size_t)(N + 1), 512);
    int* csr_src = (int*)(w + off);    off = align_up(off + sizeof(int) * (size_t)E, 512);
    uint_t* pairs = (uint_t*)(w + off); off = align_up(off + sizeof(uint_t) * (size_t)E, 512);
    ushort_t* x_bf = (ushort_t*)(w + off);   off = align_up(off + 2ull * N * D, 512);
    ushort_t* h1_bf = (ushort_t*)(w + off);  off = align_up(off + 2ull * N * D, 512);
    ushort_t* h2_bf = (ushort_t*)(w + off);  off = align_up(off + 2ull * N * D, 512);
    ushort_t* wl_bf = (ushort_t*)(w + off);  off = align_up(off + 2ull * 2 * D * D, 512);
    ushort_t* wr_bf = (ushort_t*)(w + off);  off = align_up(off + 2ull * 2 * D * D, 512);
    ushort_t* w1_bf = (ushort_t*)(w + off);  off = align_up(off + 2ull * D * D, 512);

    hipMemsetAsync(bcnt, 0, sizeof(int) * (size_t)(NB + 1), stream);

    // prep: weight casts + bucket histogram (one launch)
    const int bwl = (2 * D * D) / 2048;          // 16
    const int bwr = bwl + (2 * D * D) / 2048;    // 32
    const int bw1 = bwr + (D * D) / 2048;        // 40
    const int bin_grid = (E + BIN_CHUNK - 1) / BIN_CHUNK;   // 391
    prep_kernel<<<bw1 + bin_grid, 256, 0, stream>>>(
        lin_l_w, wl_bf, lin_r_w, wr_bf, mlp_w1, w1_bf, ei, E, bcnt, NB, bwl, bwr, bw1);

    scan_buckets_kernel<<<1, 1024, 0, stream>>>(bcnt, bptr, bcur, NB);

    // bin pass + x cast fused (x cast fills the machine during binning)
    const int bx = (N * D) / 2048;               // 6250
    bin_edges_kernel<<<bx + bin_grid, 256, 0, stream>>>(
        x, x_bf, ei, E, bcur, pairs, NB, bx);

    bucket_csr_kernel<<<NB, 256, 0, stream>>>(pairs, bptr, row_ptr, csr_src, NB, N);

    const int gemm_grid = (N + 63) / 64;

    // layer 0 (aggregation fused into the GEMM)
    sage_fused<<<gemm_grid, 256, 0, stream>>>(
        x_bf, row_ptr, csr_src, wl_bf, wr_bf, lin_l_b, lin_r_b, ln_g, ln_b, h1_bf, N);
    // layer 1
    sage_fused<<<gemm_grid, 256, 0, stream>>>(
        h1_bf, row_ptr, csr_src, wl_bf + D * D, wr_bf + D * D, lin_l_b + D, lin_r_b + D,
        ln_g + D, ln_b + D, h2_bf, N);
    // head
    mlp_head_mfma<<<gemm_grid, 256, 0, stream>>>(h2_bf, w1_bf, mlp_b1, mlp_w2, mlp_b2, out, N);
}